// Round 5
// baseline (846.401 us; speedup 1.0000x reference)
//
#include <hip/hip_runtime.h>
#include <math.h>

#define N_NODES 100000
#define N_EDGES 1600000
#define EPS_    1e-5f
#define PAD     64          // ELL row capacity; P(Poisson(16) > 64) ~ 1e-20

// grid layout for the fused kernel: every 8th block runs the lin part
#define FUSED_BLOCKS 8192
#define LIN_BLOCKS   (FUSED_BLOCKS / 8)          // 1024

// ---- bf16 helpers (raw ushort storage, RNE on pack) -----------------------
__device__ __forceinline__ float bf2f(unsigned short u) {
    union { unsigned int i; float f; } v; v.i = (unsigned int)u << 16; return v.f;
}
__device__ __forceinline__ unsigned short f2bf(float f) {
    union { float f; unsigned int i; } v; v.f = f;
    unsigned int b = v.i + 0x7FFFu + ((v.i >> 16) & 1u);   // round-to-nearest-even
    return (unsigned short)(b >> 16);
}

// ---------------------------------------------------------------------------
// Fused kernel: heterogeneous blocks.
//  * edge blocks ((bid&7)!=7): single-pass ELL build
//        pos = atomicAdd(&cnt[dst],1); ell[dst*PAD+pos] = src
//    TCC-atomic bound, VALU ~idle.
//  * lin blocks ((bid&7)==7): h = relu(x@W1+b1) -> hb_h (bf16)
//                             hg = h@Wg         -> hb_g (bf16, UNscaled)
//    VALU bound — runs in the atomic kernel's shadow. No dependence on cnt.
// ---------------------------------------------------------------------------
__global__ void build_lin_kernel(const int* __restrict__ src,
                                 const int* __restrict__ dst,
                                 const float* __restrict__ x,
                                 const float* __restrict__ W1,
                                 const float* __restrict__ b1,
                                 const float* __restrict__ Wg,
                                 int* __restrict__ cnt,
                                 int* __restrict__ ell,
                                 unsigned short* __restrict__ hb_h,
                                 unsigned short* __restrict__ hb_g)
{
    __shared__ float sWg[64 * 64];
    const int bid = blockIdx.x;
    const int tid = threadIdx.x;

    if ((bid & 7) != 7) {
        // ---- edge part ----
        const int edge_id = bid - (bid >> 3);            // compact edge index
        const int e = edge_id * 256 + tid;
        if (e < N_EDGES) {
            const int d   = dst[e];
            const int pos = atomicAdd(&cnt[d], 1);
            if (pos < PAD) ell[d * PAD + pos] = src[e];
        }
        return;
    }

    // ---- lin part ----
    for (int i = tid; i < 64 * 64; i += blockDim.x) sWg[i] = Wg[i];
    __syncthreads();                                     // block-uniform branch: legal

    const int lane   = tid & 63;
    const int lin_id = bid >> 3;                         // 0..LIN_BLOCKS-1
    const int wave   = lin_id * 4 + (tid >> 6);
    const int nwaves = LIN_BLOCKS * 4;

    for (int n = wave; n < N_NODES; n += nwaves) {
        const float x0 = x[n * 3 + 0];
        const float x1 = x[n * 3 + 1];
        const float x2 = x[n * 3 + 2];
        float h = x0 * W1[lane] + x1 * W1[64 + lane] + x2 * W1[128 + lane] + b1[lane];
        h = fmaxf(h, 0.0f);

        float acc = 0.0f;
#pragma unroll 16
        for (int k = 0; k < 64; ++k) {
            const float hk = __shfl(h, k, 64);
            acc = fmaf(hk, sWg[k * 64 + lane], acc);
        }
        hb_h[n * 64 + lane] = f2bf(h);
        hb_g[n * 64 + lane] = f2bf(acc);
    }
}

// ---------------------------------------------------------------------------
// Scale kernel: hb_g[n][c] *= rsqrt(cnt[n]+1)   (in place, bf16, ushort2 grain)
// ---------------------------------------------------------------------------
__global__ void scale_kernel(const int* __restrict__ cnt,
                             unsigned int* __restrict__ hb_g2)  // hb_g as uint
{
    const int tid = blockIdx.x * blockDim.x + threadIdx.x;
    if (tid >= N_NODES * 32) return;
    const int node = tid >> 5;
    const float di = rsqrtf((float)(cnt[node] + 1));
    const unsigned int v = hb_g2[tid];
    const float lo = bf2f((unsigned short)(v & 0xFFFFu)) * di;
    const float hi = bf2f((unsigned short)(v >> 16)) * di;
    hb_g2[tid] = (unsigned int)f2bf(lo) | ((unsigned int)f2bf(hi) << 16);
}

// ---------------------------------------------------------------------------
// Gather + epilogue. One wave per dst node, lane = channel.
//   acc = hgs[n] (self) + sum over ELL row hgs[src]     (dinv[src] pre-folded)
//   h2  = relu(dinv[n]*acc + bg)
//   out = LayerNorm128([h, h2]) * gamma + beta
// bf16 gathers: 128 B / edge (2 lines) instead of 256 B.
// ---------------------------------------------------------------------------
__global__ void gather_final_kernel(const unsigned short* __restrict__ hb_h,
                                    const unsigned short* __restrict__ hb_g,
                                    const int* __restrict__ cnt,
                                    const int* __restrict__ ell,
                                    const float* __restrict__ bg,
                                    const float* __restrict__ gamma,
                                    const float* __restrict__ beta,
                                    float* __restrict__ out)
{
    const int lane = threadIdx.x & 63;
    const int n    = blockIdx.x * (blockDim.x >> 6) + (threadIdx.x >> 6);
    if (n >= N_NODES) return;

    const int c   = cnt[n];
    const float di = rsqrtf((float)(c + 1));
    const int deg = (c < PAD) ? c : PAD;
    const int* __restrict__ row = ell + n * PAD;

    const float h = bf2f(hb_h[n * 64 + lane]);       // issue early
    float acc = bf2f(hb_g[n * 64 + lane]);           // self loop (scaled)

    int j = 0;
    for (; j + 8 <= deg; j += 8) {                   // 8 gathers in flight
        const int4 r0 = *(const int4*)(row + j);
        const int4 r1 = *(const int4*)(row + j + 4);
        const float a0 = bf2f(hb_g[r0.x * 64 + lane]);
        const float a1 = bf2f(hb_g[r0.y * 64 + lane]);
        const float a2 = bf2f(hb_g[r0.z * 64 + lane]);
        const float a3 = bf2f(hb_g[r0.w * 64 + lane]);
        const float a4 = bf2f(hb_g[r1.x * 64 + lane]);
        const float a5 = bf2f(hb_g[r1.y * 64 + lane]);
        const float a6 = bf2f(hb_g[r1.z * 64 + lane]);
        const float a7 = bf2f(hb_g[r1.w * 64 + lane]);
        acc += ((a0 + a1) + (a2 + a3)) + ((a4 + a5) + (a6 + a7));
    }
    if (j + 4 <= deg) {
        const int4 r0 = *(const int4*)(row + j);
        acc += (bf2f(hb_g[r0.x * 64 + lane]) + bf2f(hb_g[r0.y * 64 + lane]))
             + (bf2f(hb_g[r0.z * 64 + lane]) + bf2f(hb_g[r0.w * 64 + lane]));
        j += 4;
    }
    for (; j < deg; ++j) acc += bf2f(hb_g[row[j] * 64 + lane]);

    float h2 = fmaxf(fmaf(di, acc, bg[lane]), 0.0f);

    float sum = h + h2;
#pragma unroll
    for (int o = 32; o > 0; o >>= 1) sum += __shfl_xor(sum, o, 64);
    const float mu = sum * (1.0f / 128.0f);

    const float d0 = h - mu;
    const float d1 = h2 - mu;
    float vs = d0 * d0 + d1 * d1;
#pragma unroll
    for (int o = 32; o > 0; o >>= 1) vs += __shfl_xor(vs, o, 64);
    const float r = rsqrtf(vs * (1.0f / 128.0f) + EPS_);

    out[n * 128 + lane]      = d0 * r * gamma[lane]      + beta[lane];
    out[n * 128 + 64 + lane] = d1 * r * gamma[64 + lane] + beta[64 + lane];
}

// ---------------------------------------------------------------------------
extern "C" void kernel_launch(void* const* d_in, const int* in_sizes, int n_in,
                              void* d_out, int out_size, void* d_ws, size_t ws_size,
                              hipStream_t stream)
{
    const float* x     = (const float*)d_in[0];
    const int*   edge  = (const int*)  d_in[1];   // [2, E]: row0 = src, row1 = dst
    const float* W1    = (const float*)d_in[2];
    const float* b1    = (const float*)d_in[3];
    const float* Wg    = (const float*)d_in[4];
    const float* bg    = (const float*)d_in[5];
    const float* gamma = (const float*)d_in[6];
    const float* beta  = (const float*)d_in[7];
    float*       out   = (float*)d_out;

    // Workspace layout (~52 MB): hb_g | hb_h | ell | cnt   (all 16B-aligned)
    char*  ws  = (char*)d_ws;
    size_t p   = 0;
    unsigned short* hb_g = (unsigned short*)(ws + p); p += (size_t)N_NODES * 64 * sizeof(unsigned short);
    unsigned short* hb_h = (unsigned short*)(ws + p); p += (size_t)N_NODES * 64 * sizeof(unsigned short);
    int*            ell  = (int*)           (ws + p); p += (size_t)N_NODES * PAD * sizeof(int);
    int*            cnt  = (int*)           (ws + p);

    const int* src = edge;
    const int* dst = edge + N_EDGES;

    hipMemsetAsync(cnt, 0, (size_t)N_NODES * sizeof(int), stream);

    build_lin_kernel<<<FUSED_BLOCKS, 256, 0, stream>>>(src, dst, x, W1, b1, Wg,
                                                       cnt, ell, hb_h, hb_g);
    scale_kernel<<<(N_NODES * 32 + 255) / 256, 256, 0, stream>>>(cnt, (unsigned int*)hb_g);
    gather_final_kernel<<<(N_NODES + 3) / 4, 256, 0, stream>>>(hb_h, hb_g, cnt, ell,
                                                               bg, gamma, beta, out);
}

// Round 6
// 366.989 us; speedup vs baseline: 2.3063x; 2.3063x over previous
//
#include <hip/hip_runtime.h>
#include <math.h>

#define N_NODES 100000
#define N_EDGES 1600000
#define EPS_    1e-5f
#define PAD     64          // ELL row capacity; P(Poisson(16) > 64) ~ 1e-20

// ---- bf16 helpers (raw ushort storage, RNE on pack) -----------------------
__device__ __forceinline__ float bf2f(unsigned short u) {
    union { unsigned int i; float f; } v; v.i = (unsigned int)u << 16; return v.f;
}
__device__ __forceinline__ unsigned short f2bf(float f) {
    union { float f; unsigned int i; } v; v.f = f;
    unsigned int b = v.i + 0x7FFFu + ((v.i >> 16) & 1u);   // round-to-nearest-even
    return (unsigned short)(b >> 16);
}

// ---------------------------------------------------------------------------
// Kernel 1: single-pass ELL build. Pure atomic pass — no LDS, minimal VGPRs,
// so occupancy stays high and the TCC atomic pipeline stays full.
//   cnt[d] = in-degree of d;  ell[d*PAD + k] = src of k-th in-edge of d
// ---------------------------------------------------------------------------
__global__ void reorder_ell_kernel(const int* __restrict__ src,
                                   const int* __restrict__ dst,
                                   int* __restrict__ cnt,
                                   int* __restrict__ ell)
{
    const int e = blockIdx.x * blockDim.x + threadIdx.x;
    if (e >= N_EDGES) return;
    const int d   = dst[e];
    const int pos = atomicAdd(&cnt[d], 1);
    if (pos < PAD) ell[d * PAD + pos] = src[e];
}

// ---------------------------------------------------------------------------
// Kernel 2 (after ELL build, reads final cnt):
//   h   = relu(x @ W1 + b1)                  -> hb_h (bf16)
//   hgs = (h @ Wg) * rsqrt(cnt[n]+1)         -> hb_g (bf16, dinv pre-folded)
// One wave per node; lane = channel. Wg (16 KB) in LDS.
// ---------------------------------------------------------------------------
__global__ void lin_kernel(const float* __restrict__ x,
                           const float* __restrict__ W1,
                           const float* __restrict__ b1,
                           const float* __restrict__ Wg,
                           const int* __restrict__ cnt,
                           unsigned short* __restrict__ hb_h,
                           unsigned short* __restrict__ hb_g)
{
    __shared__ float sWg[64 * 64];
    for (int i = threadIdx.x; i < 64 * 64; i += blockDim.x) sWg[i] = Wg[i];
    __syncthreads();

    const int lane   = threadIdx.x & 63;
    const int wave   = blockIdx.x * (blockDim.x >> 6) + (threadIdx.x >> 6);
    const int nwaves = gridDim.x * (blockDim.x >> 6);

    for (int n = wave; n < N_NODES; n += nwaves) {
        const float x0 = x[n * 3 + 0];
        const float x1 = x[n * 3 + 1];
        const float x2 = x[n * 3 + 2];
        float h = x0 * W1[lane] + x1 * W1[64 + lane] + x2 * W1[128 + lane] + b1[lane];
        h = fmaxf(h, 0.0f);

        float acc = 0.0f;
#pragma unroll 16
        for (int k = 0; k < 64; ++k) {
            const float hk = __shfl(h, k, 64);
            acc = fmaf(hk, sWg[k * 64 + lane], acc);
        }
        const float di = rsqrtf((float)(cnt[n] + 1));   // +1 = self loop
        hb_h[n * 64 + lane] = f2bf(h);
        hb_g[n * 64 + lane] = f2bf(acc * di);
    }
}

// ---------------------------------------------------------------------------
// Kernel 3: gather + epilogue. One wave per dst node, lane = channel.
//   acc = hgs[n] (self) + sum over ELL row hgs[src]     (dinv[src] pre-folded)
//   h2  = relu(dinv[n]*acc + bg)
//   out = LayerNorm128([h, h2]) * gamma + beta
// bf16 rows are 128 B aligned -> exactly one cache line per edge gather.
// ---------------------------------------------------------------------------
__global__ void gather_final_kernel(const unsigned short* __restrict__ hb_h,
                                    const unsigned short* __restrict__ hb_g,
                                    const int* __restrict__ cnt,
                                    const int* __restrict__ ell,
                                    const float* __restrict__ bg,
                                    const float* __restrict__ gamma,
                                    const float* __restrict__ beta,
                                    float* __restrict__ out)
{
    const int lane = threadIdx.x & 63;
    const int n    = blockIdx.x * (blockDim.x >> 6) + (threadIdx.x >> 6);
    if (n >= N_NODES) return;

    const int c   = cnt[n];
    const float di = rsqrtf((float)(c + 1));
    const int deg = (c < PAD) ? c : PAD;
    const int* __restrict__ row = ell + n * PAD;

    const float h = bf2f(hb_h[n * 64 + lane]);       // issue early
    float acc = bf2f(hb_g[n * 64 + lane]);           // self loop (scaled)

    int j = 0;
    for (; j + 8 <= deg; j += 8) {                   // 8 gathers in flight
        const int4 r0 = *(const int4*)(row + j);
        const int4 r1 = *(const int4*)(row + j + 4);
        const float a0 = bf2f(hb_g[r0.x * 64 + lane]);
        const float a1 = bf2f(hb_g[r0.y * 64 + lane]);
        const float a2 = bf2f(hb_g[r0.z * 64 + lane]);
        const float a3 = bf2f(hb_g[r0.w * 64 + lane]);
        const float a4 = bf2f(hb_g[r1.x * 64 + lane]);
        const float a5 = bf2f(hb_g[r1.y * 64 + lane]);
        const float a6 = bf2f(hb_g[r1.z * 64 + lane]);
        const float a7 = bf2f(hb_g[r1.w * 64 + lane]);
        acc += ((a0 + a1) + (a2 + a3)) + ((a4 + a5) + (a6 + a7));
    }
    if (j + 4 <= deg) {
        const int4 r0 = *(const int4*)(row + j);
        acc += (bf2f(hb_g[r0.x * 64 + lane]) + bf2f(hb_g[r0.y * 64 + lane]))
             + (bf2f(hb_g[r0.z * 64 + lane]) + bf2f(hb_g[r0.w * 64 + lane]));
        j += 4;
    }
    for (; j < deg; ++j) acc += bf2f(hb_g[row[j] * 64 + lane]);

    float h2 = fmaxf(fmaf(di, acc, bg[lane]), 0.0f);

    float sum = h + h2;
#pragma unroll
    for (int o = 32; o > 0; o >>= 1) sum += __shfl_xor(sum, o, 64);
    const float mu = sum * (1.0f / 128.0f);

    const float d0 = h - mu;
    const float d1 = h2 - mu;
    float vs = d0 * d0 + d1 * d1;
#pragma unroll
    for (int o = 32; o > 0; o >>= 1) vs += __shfl_xor(vs, o, 64);
    const float r = rsqrtf(vs * (1.0f / 128.0f) + EPS_);

    out[n * 128 + lane]      = d0 * r * gamma[lane]      + beta[lane];
    out[n * 128 + 64 + lane] = d1 * r * gamma[64 + lane] + beta[64 + lane];
}

// ---------------------------------------------------------------------------
extern "C" void kernel_launch(void* const* d_in, const int* in_sizes, int n_in,
                              void* d_out, int out_size, void* d_ws, size_t ws_size,
                              hipStream_t stream)
{
    const float* x     = (const float*)d_in[0];
    const int*   edge  = (const int*)  d_in[1];   // [2, E]: row0 = src, row1 = dst
    const float* W1    = (const float*)d_in[2];
    const float* b1    = (const float*)d_in[3];
    const float* Wg    = (const float*)d_in[4];
    const float* bg    = (const float*)d_in[5];
    const float* gamma = (const float*)d_in[6];
    const float* beta  = (const float*)d_in[7];
    float*       out   = (float*)d_out;

    // Workspace layout (~51.6 MB): hb_g | hb_h | ell | cnt  (16B-aligned)
    char*  ws  = (char*)d_ws;
    size_t p   = 0;
    unsigned short* hb_g = (unsigned short*)(ws + p); p += (size_t)N_NODES * 64 * sizeof(unsigned short);
    unsigned short* hb_h = (unsigned short*)(ws + p); p += (size_t)N_NODES * 64 * sizeof(unsigned short);
    int*            ell  = (int*)           (ws + p); p += (size_t)N_NODES * PAD * sizeof(int);
    int*            cnt  = (int*)           (ws + p);

    const int* src = edge;
    const int* dst = edge + N_EDGES;

    hipMemsetAsync(cnt, 0, (size_t)N_NODES * sizeof(int), stream);

    reorder_ell_kernel<<<(N_EDGES + 255) / 256, 256, 0, stream>>>(src, dst, cnt, ell);
    lin_kernel        <<<2048, 256, 0, stream>>>(x, W1, b1, Wg, cnt, hb_h, hb_g);
    gather_final_kernel<<<(N_NODES + 3) / 4, 256, 0, stream>>>(hb_h, hb_g, cnt, ell,
                                                               bg, gamma, beta, out);
}